// Round 7
// baseline (321.629 us; speedup 1.0000x reference)
//
#include <hip/hip_runtime.h>
#include <cstdint>
#include <cstddef>
#include <cmath>

#define N_NODES 50000
#define N_EDGES 800000
#define D_FEAT 128
#define HIDDEN 128
#define N_CLASSES 40

typedef _Float16 half8 __attribute__((ext_vector_type(8)));
typedef _Float16 half4 __attribute__((ext_vector_type(4)));
typedef float f32x4 __attribute__((ext_vector_type(4)));

#define EDGE_BLOCKS 3125      // 800000 / 256
#define CVT_BLOCKS 6250       // 50000*128/4/256

// ---------------- combined build: [0,EDGE_BLOCKS) deg+rank ; rest: fp16 cvt + W swizzle ----------------

__global__ __launch_bounds__(256) void k_build(const int* __restrict__ dst, int* __restrict__ deg,
                                               unsigned short* __restrict__ rank,
                                               const float* __restrict__ x, _Float16* __restrict__ xh,
                                               const float* __restrict__ Wl0, const float* __restrict__ Wr0, _Float16* __restrict__ Wc0,
                                               const float* __restrict__ Wl1, const float* __restrict__ Wr1, _Float16* __restrict__ Wc1,
                                               const float* __restrict__ Wl2, const float* __restrict__ Wr2, _Float16* __restrict__ Wc2) {
    int bid = blockIdx.x;
    if (bid < EDGE_BLOCKS) {
        int e = bid * 256 + threadIdx.x;
        int r = atomicAdd(&deg[dst[e]], 1);
        rank[e] = (unsigned short)r;
        return;
    }
    bid -= EDGE_BLOCKS;
    if (bid < CVT_BLOCKS) {
        int i = bid * 256 + threadIdx.x;
        float4 v = *(const float4*)(x + (size_t)i * 4);
        half4 o;
        o[0] = (_Float16)v.x; o[1] = (_Float16)v.y; o[2] = (_Float16)v.z; o[3] = (_Float16)v.w;
        *(half4*)(xh + (size_t)i * 4) = o;
        return;
    }
    bid -= CVT_BLOCKS;
    const float* Wl; const float* Wr; _Float16* dstw; int NF, Nout, cell0;
    if (bid < 16)      { Wl = Wl0; Wr = Wr0; dstw = Wc0; NF = 8; Nout = 128; cell0 = bid * 4; }
    else if (bid < 32) { Wl = Wl1; Wr = Wr1; dstw = Wc1; NF = 8; Nout = 128; cell0 = (bid - 16) * 4; }
    else               { Wl = Wl2; Wr = Wr2; dstw = Wc2; NF = 3; Nout = 40;  cell0 = (bid - 32) * 4; }
    int cell = cell0 + (threadIdx.x >> 6);
    int t = cell / NF;
    int f = cell % NF;
    int l = threadIdx.x & 63;
    int kb = t * 32 + (l >> 4) * 8;
    int n = f * 16 + (l & 15);
    half8 v;
    #pragma unroll
    for (int i = 0; i < 8; ++i) {
        int k = kb + i;
        float w = 0.f;
        if (n < Nout) w = (k < 128) ? Wl[k * Nout + n] : Wr[(k - 128) * Nout + n];
        v[i] = (_Float16)w;
    }
    *(half8*)(dstw + ((size_t)cell * 64 + l) * 8) = v;
}

// ---------------- scans ----------------

__global__ __launch_bounds__(1024) void k_scan1(const int* __restrict__ deg, int* __restrict__ offsets,
                                                int* __restrict__ partials) {
    __shared__ int wsums[16];
    int tid = threadIdx.x;
    int g = blockIdx.x * 1024 + tid;
    int v = (g < N_NODES) ? deg[g] : 0;
    int lane = tid & 63;
    int wid = tid >> 6;
    int incl = v;
    #pragma unroll
    for (int off = 1; off < 64; off <<= 1) {
        int t = __shfl_up(incl, off);
        if (lane >= off) incl += t;
    }
    if (lane == 63) wsums[wid] = incl;
    __syncthreads();
    if (wid == 0) {
        int wv = (lane < 16) ? wsums[lane] : 0;
        int wincl = wv;
        #pragma unroll
        for (int off = 1; off < 16; off <<= 1) {
            int t = __shfl_up(wincl, off);
            if (lane >= off) wincl += t;
        }
        if (lane < 16) wsums[lane] = wincl - wv;
    }
    __syncthreads();
    if (g < N_NODES) offsets[g] = wsums[wid] + incl - v;
    if (tid == 1023) partials[blockIdx.x] = wsums[15] + incl;
}

__global__ __launch_bounds__(64) void k_scan2(int* __restrict__ partials, int nParts) {
    int lane = threadIdx.x;
    int v = (lane < nParts) ? partials[lane] : 0;
    int incl = v;
    #pragma unroll
    for (int off = 1; off < 64; off <<= 1) {
        int t = __shfl_up(incl, off);
        if (lane >= off) incl += t;
    }
    if (lane < nParts) partials[lane] = incl - v;
}

// scatter with inline scan3 (offsets[d] + partials[d>>10])
__global__ __launch_bounds__(256) void k_scatter(const int* __restrict__ src, const int* __restrict__ dst,
                                                 const int* __restrict__ offsets, const int* __restrict__ partials,
                                                 const unsigned short* __restrict__ rank,
                                                 unsigned short* __restrict__ sorted_src) {
    int e = blockIdx.x * 256 + threadIdx.x;
    if (e < N_EDGES) {
        int d = dst[e];
        int pos = offsets[d] + partials[d >> 10] + (int)rank[e];
        sorted_src[pos] = (unsigned short)src[e];
    }
}

// ---------------- fused layer: mean-agg (into LDS) + dual MFMA GEMM + relu ----------------
// 512 thr = 8 waves, 128 rows/block. Wave w aggregates nodes [w*16, w*16+16), writes mean
// into swizzled sA; sB staged from prev features. GEMM: wave w computes rows [w*16,w*16+16).

__device__ __forceinline__ void agg_into_lds(const _Float16* __restrict__ feat, const int* __restrict__ offsets,
                                             const int* __restrict__ partials, const int* __restrict__ deg,
                                             const unsigned short* __restrict__ sorted_src,
                                             _Float16* sA, int rows0, int tid) {
    int w = tid >> 6, lane = tid & 63;
    int grp = lane >> 4, cl = lane & 15;
    for (int j = 0; j < 16; ++j) {
        int r = w * 16 + j;
        int node = rows0 + r;
        float acc[8] = {0.f, 0.f, 0.f, 0.f, 0.f, 0.f, 0.f, 0.f};
        int cnt = 0;
        if (node < N_NODES) {
            int start = offsets[node] + partials[node >> 10];
            cnt = deg[node];
            int i = 0;
            int nfull = cnt & ~7;
            for (; i < nfull; i += 8) {
                int s0 = (int)sorted_src[start + i + grp];
                int s1 = (int)sorted_src[start + i + 4 + grp];
                half8 v0 = *(const half8*)(feat + (size_t)s0 * 128 + cl * 8);
                half8 v1 = *(const half8*)(feat + (size_t)s1 * 128 + cl * 8);
                #pragma unroll
                for (int q = 0; q < 8; ++q) acc[q] += (float)v0[q] + (float)v1[q];
            }
            for (; i < cnt; i += 4) {
                int e = i + grp;
                if (e < cnt) {
                    int s = (int)sorted_src[start + e];
                    half8 v = *(const half8*)(feat + (size_t)s * 128 + cl * 8);
                    #pragma unroll
                    for (int q = 0; q < 8; ++q) acc[q] += (float)v[q];
                }
            }
        }
        #pragma unroll
        for (int q = 0; q < 8; ++q) {
            acc[q] += __shfl_xor(acc[q], 16);
            acc[q] += __shfl_xor(acc[q], 32);
        }
        if (grp == 0) {
            float rs = 1.0f / (float)(cnt > 0 ? cnt : 1);
            half8 o;
            #pragma unroll
            for (int q = 0; q < 8; ++q) o[q] = (_Float16)(acc[q] * rs);
            *(half8*)(sA + r * 128 + (cl ^ (r & 15)) * 8) = o;
        }
    }
}

__global__ __launch_bounds__(512) void k_layer_h(const _Float16* __restrict__ feat, const int* __restrict__ offsets,
                                                 const int* __restrict__ partials, const int* __restrict__ deg,
                                                 const unsigned short* __restrict__ sorted_src,
                                                 const _Float16* __restrict__ Wc, const float* __restrict__ bias,
                                                 _Float16* __restrict__ outp) {
    __shared__ _Float16 sA[128 * 128];
    __shared__ _Float16 sB[128 * 128];
    int tid = threadIdx.x;
    int rows0 = blockIdx.x * 128;
    // stage B tile (prev features, coalesced)
    #pragma unroll
    for (int i = 0; i < 4; ++i) {
        int cid = i * 512 + tid;
        int r = cid >> 4, ch = cid & 15;
        int gr = rows0 + r;
        int grc = gr < N_NODES ? gr : N_NODES - 1;
        half8 v = *(const half8*)(feat + (size_t)grc * 128 + ch * 8);
        *(half8*)(sB + r * 128 + (ch ^ (r & 15)) * 8) = v;
    }
    agg_into_lds(feat, offsets, partials, deg, sorted_src, sA, rows0, tid);
    __syncthreads();
    int w = tid >> 6, lane = tid & 63;
    int ln = lane & 15, lg = lane >> 4;
    int r0 = w * 16 + ln;
    f32x4 acc[8];
    #pragma unroll
    for (int f = 0; f < 8; ++f) acc[f] = (f32x4){0.f, 0.f, 0.f, 0.f};
    #pragma unroll
    for (int t = 0; t < 8; ++t) {
        const _Float16* P = (t < 4) ? sA : sB;
        int ch = (t & 3) * 4 + lg;
        half8 a = *(const half8*)(P + r0 * 128 + (ch ^ (r0 & 15)) * 8);
        #pragma unroll
        for (int f = 0; f < 8; ++f) {
            half8 b = *(const half8*)(Wc + ((size_t)(t * 8 + f) * 64 + lane) * 8);
            acc[f] = __builtin_amdgcn_mfma_f32_16x16x32_f16(a, b, acc[f], 0, 0, 0);
        }
    }
    int rw = rows0 + w * 16;
    #pragma unroll
    for (int f = 0; f < 8; ++f) {
        int n = f * 16 + ln;
        float bv = bias[n];
        #pragma unroll
        for (int r = 0; r < 4; ++r) {
            int m = rw + lg * 4 + r;
            if (m < N_NODES) {
                float v = fmaxf(acc[f][r] + bv, 0.f);
                outp[(size_t)m * 128 + n] = (_Float16)v;
            }
        }
    }
}

__global__ __launch_bounds__(512) void k_layer_f(const _Float16* __restrict__ feat, const int* __restrict__ offsets,
                                                 const int* __restrict__ partials, const int* __restrict__ deg,
                                                 const unsigned short* __restrict__ sorted_src,
                                                 const _Float16* __restrict__ Wc, const float* __restrict__ bias,
                                                 float* __restrict__ outp) {
    __shared__ _Float16 sA[128 * 128];
    __shared__ _Float16 sB[128 * 128];
    int tid = threadIdx.x;
    int rows0 = blockIdx.x * 128;
    #pragma unroll
    for (int i = 0; i < 4; ++i) {
        int cid = i * 512 + tid;
        int r = cid >> 4, ch = cid & 15;
        int gr = rows0 + r;
        int grc = gr < N_NODES ? gr : N_NODES - 1;
        half8 v = *(const half8*)(feat + (size_t)grc * 128 + ch * 8);
        *(half8*)(sB + r * 128 + (ch ^ (r & 15)) * 8) = v;
    }
    agg_into_lds(feat, offsets, partials, deg, sorted_src, sA, rows0, tid);
    __syncthreads();
    int w = tid >> 6, lane = tid & 63;
    int ln = lane & 15, lg = lane >> 4;
    int r0 = w * 16 + ln;
    f32x4 acc[3];
    #pragma unroll
    for (int f = 0; f < 3; ++f) acc[f] = (f32x4){0.f, 0.f, 0.f, 0.f};
    #pragma unroll
    for (int t = 0; t < 8; ++t) {
        const _Float16* P = (t < 4) ? sA : sB;
        int ch = (t & 3) * 4 + lg;
        half8 a = *(const half8*)(P + r0 * 128 + (ch ^ (r0 & 15)) * 8);
        #pragma unroll
        for (int f = 0; f < 3; ++f) {
            half8 b = *(const half8*)(Wc + ((size_t)(t * 3 + f) * 64 + lane) * 8);
            acc[f] = __builtin_amdgcn_mfma_f32_16x16x32_f16(a, b, acc[f], 0, 0, 0);
        }
    }
    float bv[3];
    #pragma unroll
    for (int f = 0; f < 3; ++f) {
        int n = f * 16 + ln;
        bv[f] = (n < N_CLASSES) ? bias[n] : 0.f;
    }
    int rw = rows0 + w * 16;
    #pragma unroll
    for (int r = 0; r < 4; ++r) {
        int m = rw + lg * 4 + r;
        float v[3];
        float vmax = -INFINITY;
        #pragma unroll
        for (int f = 0; f < 3; ++f) {
            int n = f * 16 + ln;
            v[f] = fmaxf(acc[f][r] + bv[f], 0.f);
            if (n < N_CLASSES) vmax = fmaxf(vmax, v[f]);
        }
        #pragma unroll
        for (int off = 1; off < 16; off <<= 1) vmax = fmaxf(vmax, __shfl_xor(vmax, off));
        float s = 0.f;
        #pragma unroll
        for (int f = 0; f < 3; ++f) {
            int n = f * 16 + ln;
            if (n < N_CLASSES) s += expf(v[f] - vmax);
        }
        #pragma unroll
        for (int off = 1; off < 16; off <<= 1) s += __shfl_xor(s, off);
        float lse = vmax + logf(s);
        if (m < N_NODES) {
            #pragma unroll
            for (int f = 0; f < 3; ++f) {
                int n = f * 16 + ln;
                if (n < N_CLASSES) outp[(size_t)m * N_CLASSES + n] = v[f] - lse;
            }
        }
    }
}

extern "C" void kernel_launch(void* const* d_in, const int* in_sizes, int n_in,
                              void* d_out, int out_size, void* d_ws, size_t ws_size,
                              hipStream_t stream) {
    const float* x   = (const float*)d_in[0];
    const int*   ei  = (const int*)d_in[1];
    const float* Wl0 = (const float*)d_in[2];
    const float* bl0 = (const float*)d_in[3];
    const float* Wr0 = (const float*)d_in[4];
    const float* Wl1 = (const float*)d_in[5];
    const float* bl1 = (const float*)d_in[6];
    const float* Wr1 = (const float*)d_in[7];
    const float* Wl2 = (const float*)d_in[8];
    const float* bl2 = (const float*)d_in[9];
    const float* Wr2 = (const float*)d_in[10];
    float* out = (float*)d_out;

    const int* src = ei;
    const int* dst = ei + N_EDGES;

    // workspace layout
    int* offsets  = (int*)d_ws;                                  // 50016 ints
    int* deg      = offsets + 50016;                             // 50016 ints
    int* partials = deg + 50016;                                 // 64 ints
    unsigned short* rank   = (unsigned short*)(partials + 64);   // 800k u16
    unsigned short* sorted = rank + N_EDGES;                     // 800k u16
    _Float16* xh  = (_Float16*)(sorted + N_EDGES);
    _Float16* h0  = xh + (size_t)N_NODES * 128;
    _Float16* h1  = h0 + (size_t)N_NODES * 128;
    _Float16* Wc0 = h1 + (size_t)N_NODES * 128;
    _Float16* Wc1 = Wc0 + 8 * 8 * 64 * 8;
    _Float16* Wc2 = Wc1 + 8 * 8 * 64 * 8;

    hipMemsetAsync(deg, 0, 50016 * sizeof(int), stream);

    const int scanBlocks = (N_NODES + 1023) / 1024;
    k_build<<<EDGE_BLOCKS + CVT_BLOCKS + 38, 256, 0, stream>>>(dst, deg, rank, x, xh,
                                                               Wl0, Wr0, Wc0, Wl1, Wr1, Wc1, Wl2, Wr2, Wc2);
    k_scan1<<<scanBlocks, 1024, 0, stream>>>(deg, offsets, partials);
    k_scan2<<<1, 64, 0, stream>>>(partials, scanBlocks);
    k_scatter<<<EDGE_BLOCKS, 256, 0, stream>>>(src, dst, offsets, partials, rank, sorted);

    const int layerBlocks = (N_NODES + 127) / 128;
    k_layer_h<<<layerBlocks, 512, 0, stream>>>(xh, offsets, partials, deg, sorted, Wc0, bl0, h0);
    k_layer_h<<<layerBlocks, 512, 0, stream>>>(h0, offsets, partials, deg, sorted, Wc1, bl1, h1);
    k_layer_f<<<layerBlocks, 512, 0, stream>>>(h1, offsets, partials, deg, sorted, Wc2, bl2, out);
}

// Round 9
// 279.074 us; speedup vs baseline: 1.1525x; 1.1525x over previous
//
#include <hip/hip_runtime.h>
#include <cstdint>
#include <cstddef>
#include <cmath>

#define N_NODES 50000
#define N_EDGES 800000
#define D_FEAT 128
#define HIDDEN 128
#define N_CLASSES 40

typedef _Float16 half8 __attribute__((ext_vector_type(8)));
typedef _Float16 half4 __attribute__((ext_vector_type(4)));
typedef float f32x4 __attribute__((ext_vector_type(4)));

#define EDGE_BLOCKS 3125      // 800000 / 256
#define CVT_BLOCKS 6250       // 50000*128/4/256

// ---------------- combined build: [0,EDGE_BLOCKS) deg+rank ; rest: fp16 cvt + W swizzle ----------------

__global__ __launch_bounds__(256) void k_build(const int* __restrict__ dst, int* __restrict__ deg,
                                               unsigned short* __restrict__ rank,
                                               const float* __restrict__ x, _Float16* __restrict__ xh,
                                               const float* __restrict__ Wl0, const float* __restrict__ Wr0, _Float16* __restrict__ Wc0,
                                               const float* __restrict__ Wl1, const float* __restrict__ Wr1, _Float16* __restrict__ Wc1,
                                               const float* __restrict__ Wl2, const float* __restrict__ Wr2, _Float16* __restrict__ Wc2) {
    int bid = blockIdx.x;
    if (bid < EDGE_BLOCKS) {
        int e = bid * 256 + threadIdx.x;
        int r = atomicAdd(&deg[dst[e]], 1);
        rank[e] = (unsigned short)r;
        return;
    }
    bid -= EDGE_BLOCKS;
    if (bid < CVT_BLOCKS) {
        int i = bid * 256 + threadIdx.x;
        float4 v = *(const float4*)(x + (size_t)i * 4);
        half4 o;
        o[0] = (_Float16)v.x; o[1] = (_Float16)v.y; o[2] = (_Float16)v.z; o[3] = (_Float16)v.w;
        *(half4*)(xh + (size_t)i * 4) = o;
        return;
    }
    bid -= CVT_BLOCKS;
    const float* Wl; const float* Wr; _Float16* dstw; int NF, Nout, cell0;
    if (bid < 16)      { Wl = Wl0; Wr = Wr0; dstw = Wc0; NF = 8; Nout = 128; cell0 = bid * 4; }
    else if (bid < 32) { Wl = Wl1; Wr = Wr1; dstw = Wc1; NF = 8; Nout = 128; cell0 = (bid - 16) * 4; }
    else               { Wl = Wl2; Wr = Wr2; dstw = Wc2; NF = 3; Nout = 40;  cell0 = (bid - 32) * 4; }
    int cell = cell0 + (threadIdx.x >> 6);
    int t = cell / NF;
    int f = cell % NF;
    int l = threadIdx.x & 63;
    int kb = t * 32 + (l >> 4) * 8;
    int n = f * 16 + (l & 15);
    half8 v;
    #pragma unroll
    for (int i = 0; i < 8; ++i) {
        int k = kb + i;
        float w = 0.f;
        if (n < Nout) w = (k < 128) ? Wl[k * Nout + n] : Wr[(k - 128) * Nout + n];
        v[i] = (_Float16)w;
    }
    *(half8*)(dstw + ((size_t)cell * 64 + l) * 8) = v;
}

// ---------------- scans ----------------

__global__ __launch_bounds__(1024) void k_scan1(const int* __restrict__ deg, int* __restrict__ offsets,
                                                int* __restrict__ partials) {
    __shared__ int wsums[16];
    int tid = threadIdx.x;
    int g = blockIdx.x * 1024 + tid;
    int v = (g < N_NODES) ? deg[g] : 0;
    int lane = tid & 63;
    int wid = tid >> 6;
    int incl = v;
    #pragma unroll
    for (int off = 1; off < 64; off <<= 1) {
        int t = __shfl_up(incl, off);
        if (lane >= off) incl += t;
    }
    if (lane == 63) wsums[wid] = incl;
    __syncthreads();
    if (wid == 0) {
        int wv = (lane < 16) ? wsums[lane] : 0;
        int wincl = wv;
        #pragma unroll
        for (int off = 1; off < 16; off <<= 1) {
            int t = __shfl_up(wincl, off);
            if (lane >= off) wincl += t;
        }
        if (lane < 16) wsums[lane] = wincl - wv;
    }
    __syncthreads();
    if (g < N_NODES) offsets[g] = wsums[wid] + incl - v;
    if (tid == 1023) partials[blockIdx.x] = wsums[15] + incl;
}

__global__ __launch_bounds__(64) void k_scan2(int* __restrict__ partials, int nParts) {
    int lane = threadIdx.x;
    int v = (lane < nParts) ? partials[lane] : 0;
    int incl = v;
    #pragma unroll
    for (int off = 1; off < 64; off <<= 1) {
        int t = __shfl_up(incl, off);
        if (lane >= off) incl += t;
    }
    if (lane < nParts) partials[lane] = incl - v;
}

// scatter with inline scan3 (offsets[d] + partials[d>>10])
__global__ __launch_bounds__(256) void k_scatter(const int* __restrict__ src, const int* __restrict__ dst,
                                                 const int* __restrict__ offsets, const int* __restrict__ partials,
                                                 const unsigned short* __restrict__ rank,
                                                 unsigned short* __restrict__ sorted_src) {
    int e = blockIdx.x * 256 + threadIdx.x;
    if (e < N_EDGES) {
        int d = dst[e];
        int pos = offsets[d] + partials[d >> 10] + (int)rank[e];
        sorted_src[pos] = (unsigned short)src[e];
    }
}

// ---------------- mean aggregation: one 16-lane group per node (4 nodes/wave) ----------------
// group: 16 lanes x 16B = full 256B row per gather; private loop, no cross-group reduce.

__global__ __launch_bounds__(256) void k_agg_h(const _Float16* __restrict__ feat, const int* __restrict__ offsets,
                                               const int* __restrict__ partials, const int* __restrict__ deg,
                                               const unsigned short* __restrict__ sorted_src,
                                               _Float16* __restrict__ mean) {
    int node = (int)((blockIdx.x * 256 + threadIdx.x) >> 4);
    int cl = threadIdx.x & 15;
    if (node >= N_NODES) return;
    int start = offsets[node] + partials[node >> 10];
    int cnt = deg[node];
    float acc[8] = {0.f, 0.f, 0.f, 0.f, 0.f, 0.f, 0.f, 0.f};
    #pragma unroll 4
    for (int e = 0; e < cnt; ++e) {
        int s = (int)sorted_src[start + e];
        half8 v = *(const half8*)(feat + (size_t)s * 128 + cl * 8);
        #pragma unroll
        for (int q = 0; q < 8; ++q) acc[q] += (float)v[q];
    }
    float r = 1.0f / (float)(cnt > 0 ? cnt : 1);
    half8 o;
    #pragma unroll
    for (int q = 0; q < 8; ++q) o[q] = (_Float16)(acc[q] * r);
    *(half8*)(mean + (size_t)node * 128 + cl * 8) = o;
}

// ---------------- hidden layer MFMA GEMM with LDS-staged A/B tiles ----------------
// block: 256 thr = 4 waves, 128 rows; LDS: sA/sB 128x128 fp16, chunk^row swizzle

__global__ __launch_bounds__(256) void k_gemm_h(const _Float16* __restrict__ A, const _Float16* __restrict__ B,
                                                const _Float16* __restrict__ Wc, const float* __restrict__ bias,
                                                _Float16* __restrict__ outp) {
    __shared__ _Float16 sA[128 * 128];
    __shared__ _Float16 sB[128 * 128];
    int tid = threadIdx.x;
    int rows0 = blockIdx.x * 128;
    for (int i = 0; i < 8; ++i) {
        int cid = i * 256 + tid;
        int r = cid >> 4;
        int ch = cid & 15;
        int gr = rows0 + r;
        int grc = gr < N_NODES ? gr : N_NODES - 1;
        half8 va = *(const half8*)(A + (size_t)grc * 128 + ch * 8);
        half8 vb = *(const half8*)(B + (size_t)grc * 128 + ch * 8);
        int sch = ch ^ (r & 15);
        *(half8*)(sA + r * 128 + sch * 8) = va;
        *(half8*)(sB + r * 128 + sch * 8) = vb;
    }
    __syncthreads();
    int w = tid >> 6;
    int lane = tid & 63;
    int ln = lane & 15, lg = lane >> 4;
    int r0 = w * 32 + ln;
    int r1 = r0 + 16;
    f32x4 acc[2][8];
    #pragma unroll
    for (int i = 0; i < 2; ++i)
        #pragma unroll
        for (int f = 0; f < 8; ++f) acc[i][f] = (f32x4){0.f, 0.f, 0.f, 0.f};
    #pragma unroll
    for (int t = 0; t < 8; ++t) {
        const _Float16* P = (t < 4) ? sA : sB;
        int ch = (t & 3) * 4 + lg;
        half8 a0 = *(const half8*)(P + r0 * 128 + (ch ^ (r0 & 15)) * 8);
        half8 a1 = *(const half8*)(P + r1 * 128 + (ch ^ (r1 & 15)) * 8);
        #pragma unroll
        for (int f = 0; f < 8; ++f) {
            half8 b = *(const half8*)(Wc + ((size_t)(t * 8 + f) * 64 + lane) * 8);
            acc[0][f] = __builtin_amdgcn_mfma_f32_16x16x32_f16(a0, b, acc[0][f], 0, 0, 0);
            acc[1][f] = __builtin_amdgcn_mfma_f32_16x16x32_f16(a1, b, acc[1][f], 0, 0, 0);
        }
    }
    int rw = rows0 + w * 32;
    #pragma unroll
    for (int mf = 0; mf < 2; ++mf) {
        #pragma unroll
        for (int f = 0; f < 8; ++f) {
            int n = f * 16 + ln;
            float bv = bias[n];
            #pragma unroll
            for (int r = 0; r < 4; ++r) {
                int m = rw + mf * 16 + lg * 4 + r;
                if (m < N_NODES) {
                    float v = fmaxf(acc[mf][f][r] + bv, 0.f);
                    outp[(size_t)m * 128 + n] = (_Float16)v;
                }
            }
        }
    }
}

// ---------------- final layer MFMA GEMM (N=40 pad 48) + relu + log_softmax, LDS-staged ----------------

__global__ __launch_bounds__(256) void k_gemm_f(const _Float16* __restrict__ A, const _Float16* __restrict__ B,
                                                const _Float16* __restrict__ Wc, const float* __restrict__ bias,
                                                float* __restrict__ outp) {
    __shared__ _Float16 sA[128 * 128];
    __shared__ _Float16 sB[128 * 128];
    int tid = threadIdx.x;
    int rows0 = blockIdx.x * 128;
    for (int i = 0; i < 8; ++i) {
        int cid = i * 256 + tid;
        int r = cid >> 4;
        int ch = cid & 15;
        int gr = rows0 + r;
        int grc = gr < N_NODES ? gr : N_NODES - 1;
        half8 va = *(const half8*)(A + (size_t)grc * 128 + ch * 8);
        half8 vb = *(const half8*)(B + (size_t)grc * 128 + ch * 8);
        int sch = ch ^ (r & 15);
        *(half8*)(sA + r * 128 + sch * 8) = va;
        *(half8*)(sB + r * 128 + sch * 8) = vb;
    }
    __syncthreads();
    int w = tid >> 6;
    int lane = tid & 63;
    int ln = lane & 15, lg = lane >> 4;
    int r0 = w * 32 + ln;
    int r1 = r0 + 16;
    f32x4 acc[2][3];
    #pragma unroll
    for (int i = 0; i < 2; ++i)
        #pragma unroll
        for (int f = 0; f < 3; ++f) acc[i][f] = (f32x4){0.f, 0.f, 0.f, 0.f};
    #pragma unroll
    for (int t = 0; t < 8; ++t) {
        const _Float16* P = (t < 4) ? sA : sB;
        int ch = (t & 3) * 4 + lg;
        half8 a0 = *(const half8*)(P + r0 * 128 + (ch ^ (r0 & 15)) * 8);
        half8 a1 = *(const half8*)(P + r1 * 128 + (ch ^ (r1 & 15)) * 8);
        #pragma unroll
        for (int f = 0; f < 3; ++f) {
            half8 b = *(const half8*)(Wc + ((size_t)(t * 3 + f) * 64 + lane) * 8);
            acc[0][f] = __builtin_amdgcn_mfma_f32_16x16x32_f16(a0, b, acc[0][f], 0, 0, 0);
            acc[1][f] = __builtin_amdgcn_mfma_f32_16x16x32_f16(a1, b, acc[1][f], 0, 0, 0);
        }
    }
    float bv[3];
    #pragma unroll
    for (int f = 0; f < 3; ++f) {
        int n = f * 16 + ln;
        bv[f] = (n < N_CLASSES) ? bias[n] : 0.f;
    }
    int rw = rows0 + w * 32;
    #pragma unroll
    for (int mf = 0; mf < 2; ++mf) {
        #pragma unroll
        for (int r = 0; r < 4; ++r) {
            int m = rw + mf * 16 + lg * 4 + r;
            float v[3];
            float vmax = -INFINITY;
            #pragma unroll
            for (int f = 0; f < 3; ++f) {
                int n = f * 16 + ln;
                v[f] = fmaxf(acc[mf][f][r] + bv[f], 0.f);
                if (n < N_CLASSES) vmax = fmaxf(vmax, v[f]);
            }
            #pragma unroll
            for (int off = 1; off < 16; off <<= 1) vmax = fmaxf(vmax, __shfl_xor(vmax, off));
            float s = 0.f;
            #pragma unroll
            for (int f = 0; f < 3; ++f) {
                int n = f * 16 + ln;
                if (n < N_CLASSES) s += expf(v[f] - vmax);
            }
            #pragma unroll
            for (int off = 1; off < 16; off <<= 1) s += __shfl_xor(s, off);
            float lse = vmax + logf(s);
            if (m < N_NODES) {
                #pragma unroll
                for (int f = 0; f < 3; ++f) {
                    int n = f * 16 + ln;
                    if (n < N_CLASSES) outp[(size_t)m * N_CLASSES + n] = v[f] - lse;
                }
            }
        }
    }
}

extern "C" void kernel_launch(void* const* d_in, const int* in_sizes, int n_in,
                              void* d_out, int out_size, void* d_ws, size_t ws_size,
                              hipStream_t stream) {
    const float* x   = (const float*)d_in[0];
    const int*   ei  = (const int*)d_in[1];
    const float* Wl0 = (const float*)d_in[2];
    const float* bl0 = (const float*)d_in[3];
    const float* Wr0 = (const float*)d_in[4];
    const float* Wl1 = (const float*)d_in[5];
    const float* bl1 = (const float*)d_in[6];
    const float* Wr1 = (const float*)d_in[7];
    const float* Wl2 = (const float*)d_in[8];
    const float* bl2 = (const float*)d_in[9];
    const float* Wr2 = (const float*)d_in[10];
    float* out = (float*)d_out;

    const int* src = ei;
    const int* dst = ei + N_EDGES;

    // workspace layout
    int* offsets  = (int*)d_ws;                                  // 50016 ints
    int* deg      = offsets + 50016;                             // 50016 ints
    int* partials = deg + 50016;                                 // 64 ints
    unsigned short* rank   = (unsigned short*)(partials + 64);   // 800k u16
    unsigned short* sorted = rank + N_EDGES;                     // 800k u16
    _Float16* xh  = (_Float16*)(sorted + N_EDGES);
    _Float16* mh  = xh + (size_t)N_NODES * 128;
    _Float16* h0  = mh + (size_t)N_NODES * 128;
    _Float16* h1  = h0 + (size_t)N_NODES * 128;
    _Float16* Wc0 = h1 + (size_t)N_NODES * 128;
    _Float16* Wc1 = Wc0 + 8 * 8 * 64 * 8;
    _Float16* Wc2 = Wc1 + 8 * 8 * 64 * 8;

    hipMemsetAsync(deg, 0, 50016 * sizeof(int), stream);

    const int scanBlocks = (N_NODES + 1023) / 1024;
    k_build<<<EDGE_BLOCKS + CVT_BLOCKS + 38, 256, 0, stream>>>(dst, deg, rank, x, xh,
                                                               Wl0, Wr0, Wc0, Wl1, Wr1, Wc1, Wl2, Wr2, Wc2);
    k_scan1<<<scanBlocks, 1024, 0, stream>>>(deg, offsets, partials);
    k_scan2<<<1, 64, 0, stream>>>(partials, scanBlocks);
    k_scatter<<<EDGE_BLOCKS, 256, 0, stream>>>(src, dst, offsets, partials, rank, sorted);

    const int aggBlocks  = (N_NODES * 16 + 255) / 256;   // 3125
    const int gemmBlocks = (N_NODES + 127) / 128;        // 391

    // layer 0
    k_agg_h<<<aggBlocks, 256, 0, stream>>>(xh, offsets, partials, deg, sorted, mh);
    k_gemm_h<<<gemmBlocks, 256, 0, stream>>>(mh, xh, Wc0, bl0, h0);
    // layer 1
    k_agg_h<<<aggBlocks, 256, 0, stream>>>(h0, offsets, partials, deg, sorted, mh);
    k_gemm_h<<<gemmBlocks, 256, 0, stream>>>(mh, h0, Wc1, bl1, h1);
    // layer 2 + log_softmax
    k_agg_h<<<aggBlocks, 256, 0, stream>>>(h1, offsets, partials, deg, sorted, mh);
    k_gemm_f<<<gemmBlocks, 256, 0, stream>>>(mh, h1, Wc2, bl2, out);
}